// Round 2
// baseline (503.427 us; speedup 1.0000x reference)
//
#include <hip/hip_runtime.h>
#include <hip/hip_bf16.h>

// Problem constants
#define TT 128
#define EE 192
#define HH 192
// SCALE = E^-0.5 = 192^-0.5
#define SCALE_F 0.07216878364870322f
#define LOG2E_F 1.4426950408889634f

typedef float f32x4 __attribute__((ext_vector_type(4)));
typedef short short8 __attribute__((ext_vector_type(8)));
typedef short short4v __attribute__((ext_vector_type(4)));

__device__ inline unsigned short f2bf(float x) {
  union { float f; unsigned u; } v; v.f = x;
  unsigned r = v.u + 0x7FFFu + ((v.u >> 16) & 1u);
  return (unsigned short)(r >> 16);
}

// ---- LDS layout (bytes) ----
// x/Q/P region at 0 : [128][192+8] bf16 stride 400 (x, then Q, then P at stride 272)
// K at 51200        : [128][192+8] bf16 stride 400 (row-major [t][h])
// V^T at 102400     : [192][128+8] bf16 stride 272 ([h][t])
// pmx at 154624     : [128][2] f32 partial max
// psum at 155648    : [128][2] f32 partial sum
#define XO 0
#define XS 400
#define KO 51200
#define VO 102400
#define VS 272
#define PS 272
#define PMO 154624
#define PSO 155648
#define LDS_TOTAL 156672

// ---- kernel 0: convert weights fp32 -> bf16 into workspace ----
// ws shorts: Wq [0,36864), Wk [36864,73728), Wv [73728,110592)  ([h][e] layout)
__global__ void cvt_w(const float* __restrict__ Wq, const float* __restrict__ Wk,
                      const float* __restrict__ Wv, short* __restrict__ out) {
  int idx = blockIdx.x * 256 + threadIdx.x;  // float4 index, 27648 total
  const float* src; int base;
  if (idx < 9216) { src = Wq; base = 0; }
  else if (idx < 18432) { src = Wk; base = 9216; }
  else { src = Wv; base = 18432; }
  float4 f = ((const float4*)src)[idx - base];
  short4v h;
  h[0] = (short)f2bf(f.x); h[1] = (short)f2bf(f.y);
  h[2] = (short)f2bf(f.z); h[3] = (short)f2bf(f.w);
  *(short4v*)(out + idx * 4) = h;
}

// One projection for 16-wave division: wave owns m-tile mt (rows mt*16..+15)
// and n-slabs {ns0, ns0+2} (cols ns*48..+47 each).
// MFMA 16x16x32 bf16: A lane l: A[m=l&15][k=(l>>4)*8+j]; B lane l: B[k][n=l&15];
// D lane l: D[m=(l>>4)*4+r][n=l&15].  B[k=e][n=h] = W[h][e] (torch Linear x W^T).
__device__ inline void proj16(const short* __restrict__ Wb, const char* xs,
                              int mt, int ns0, int lg, int lr, f32x4 acc[2][3]) {
  const f32x4 zero = {0.f, 0.f, 0.f, 0.f};
#pragma unroll
  for (int si = 0; si < 2; ++si)
#pragma unroll
    for (int nt = 0; nt < 3; ++nt) acc[si][nt] = zero;
#pragma unroll
  for (int kt = 0; kt < 6; ++kt) {
    int e0 = kt * 32 + lg * 8;
    short8 a = *(const short8*)(xs + (mt * 16 + lr) * XS + e0 * 2);
#pragma unroll
    for (int si = 0; si < 2; ++si) {
      int ns = ns0 + si * 2;
#pragma unroll
      for (int nt = 0; nt < 3; ++nt) {
        int h = ns * 48 + nt * 16 + lr;
        short8 b = *(const short8*)(Wb + h * EE + e0);
        acc[si][nt] = __builtin_amdgcn_mfma_f32_16x16x32_bf16(a, b, acc[si][nt], 0, 0, 0);
      }
    }
  }
}

__global__ __launch_bounds__(1024, 4)
void head_kernel(const float* __restrict__ x, const short* __restrict__ wsW,
                 float* __restrict__ out) {
  extern __shared__ char smem[];
  float* pmx  = (float*)(smem + PMO);
  float* psum = (float*)(smem + PSO);
  const int b = blockIdx.x;
  const int tid = threadIdx.x;
  const int wid = tid >> 6, lane = tid & 63;
  const int lg = lane >> 4, lr = lane & 15;
  const int mt = wid & 7, ns0 = wid >> 3;   // projection division
  const int qt = wid >> 1, half = wid & 1;  // attention division

  const short* Wqb = wsW;
  const short* Wkb = wsW + 36864;
  const short* Wvb = wsW + 73728;

  // ---- Phase 1: stage x[b] -> LDS bf16 ----
  const float4* xb4 = (const float4*)(x + (size_t)b * (TT * EE));
#pragma unroll
  for (int i = 0; i < 6; ++i) {
    int fi = tid + i * 1024;          // float4 index, 6144 total
    float4 f = xb4[fi];
    int row = fi / 48, c4 = fi % 48;  // 48 float4 per row of 192
    short4v h4;
    h4[0] = (short)f2bf(f.x); h4[1] = (short)f2bf(f.y);
    h4[2] = (short)f2bf(f.z); h4[3] = (short)f2bf(f.w);
    *(short4v*)(smem + XO + row * XS + c4 * 8) = h4;
  }
  __syncthreads();  // B1

  f32x4 acc[2][3];

  // ---- K projection -> K region [t][h] ----
  proj16(Wkb, smem + XO, mt, ns0, lg, lr, acc);
#pragma unroll
  for (int si = 0; si < 2; ++si)
#pragma unroll
    for (int nt = 0; nt < 3; ++nt) {
      int h = (ns0 + si * 2) * 48 + nt * 16 + lr;
#pragma unroll
      for (int r = 0; r < 4; ++r) {
        int t = mt * 16 + lg * 4 + r;
        *(unsigned short*)(smem + KO + t * XS + h * 2) = f2bf(acc[si][nt][r]);
      }
    }

  // ---- V projection -> V^T region [h][t] (4 consecutive t per lane) ----
  proj16(Wvb, smem + XO, mt, ns0, lg, lr, acc);
#pragma unroll
  for (int si = 0; si < 2; ++si)
#pragma unroll
    for (int nt = 0; nt < 3; ++nt) {
      int h = (ns0 + si * 2) * 48 + nt * 16 + lr;
      int t0 = mt * 16 + lg * 4;
      short4v p;
      p[0] = (short)f2bf(acc[si][nt][0]); p[1] = (short)f2bf(acc[si][nt][1]);
      p[2] = (short)f2bf(acc[si][nt][2]); p[3] = (short)f2bf(acc[si][nt][3]);
      *(short4v*)(smem + VO + h * VS + t0 * 2) = p;
    }

  // ---- Q projection -> regs, write to x region after barrier ----
  f32x4 accq[2][3];
  proj16(Wqb, smem + XO, mt, ns0, lg, lr, accq);
  __syncthreads();  // B2: all x reads done; K/V writes visible
#pragma unroll
  for (int si = 0; si < 2; ++si)
#pragma unroll
    for (int nt = 0; nt < 3; ++nt) {
      int h = (ns0 + si * 2) * 48 + nt * 16 + lr;
#pragma unroll
      for (int r = 0; r < 4; ++r) {
        int t = mt * 16 + lg * 4 + r;
        *(unsigned short*)(smem + XO + t * XS + h * 2) = f2bf(accq[si][nt][r]);
      }
    }
  __syncthreads();  // B3: Q visible

  // ---- QK^T: wave (qt,half) computes col tiles nt = 2j+half, j=0..3 ----
  f32x4 s[4];
  const f32x4 zero = {0.f, 0.f, 0.f, 0.f};
#pragma unroll
  for (int j = 0; j < 4; ++j) s[j] = zero;
#pragma unroll
  for (int kt = 0; kt < 6; ++kt) {
    int e0 = kt * 32 + lg * 8;
    short8 a = *(const short8*)(smem + XO + (qt * 16 + lr) * XS + e0 * 2);  // Q
#pragma unroll
    for (int j = 0; j < 4; ++j) {
      int nt = 2 * j + half;
      if (nt <= qt) {  // skip fully-masked tiles
        short8 bb = *(const short8*)(smem + KO + (nt * 16 + lr) * XS + e0 * 2);
        s[j] = __builtin_amdgcn_mfma_f32_16x16x32_bf16(a, bb, s[j], 0, 0, 0);
      }
    }
  }

  // ---- partial max over this wave's 64 cols ----
  const float CSC = SCALE_F * LOG2E_F;
  float pv[4][4];
#pragma unroll
  for (int r = 0; r < 4; ++r) {
    int q = qt * 16 + lg * 4 + r;
    float pm = -INFINITY;
#pragma unroll
    for (int j = 0; j < 4; ++j) {
      int c = (2 * j + half) * 16 + lr;
      float v = s[j][r] * CSC;
      v = (c <= q) ? v : -INFINITY;
      pv[r][j] = v;
      pm = fmaxf(pm, v);
    }
    pm = fmaxf(pm, __shfl_xor(pm, 1));
    pm = fmaxf(pm, __shfl_xor(pm, 2));
    pm = fmaxf(pm, __shfl_xor(pm, 4));
    pm = fmaxf(pm, __shfl_xor(pm, 8));
    if (lr == 0) pmx[q * 2 + half] = pm;
  }
  __syncthreads();  // B4: pmx visible; all Q/K reads done

  // ---- global max, exp, partial sums, write unnormalized P bf16 ----
#pragma unroll
  for (int r = 0; r < 4; ++r) {
    int q = qt * 16 + lg * 4 + r;
    float m = fmaxf(pmx[q * 2], pmx[q * 2 + 1]);
    float ps = 0.f;
#pragma unroll
    for (int j = 0; j < 4; ++j) {
      float p = exp2f(pv[r][j] - m);  // masked -> exp2(-inf) = 0
      pv[r][j] = p;
      ps += p;
    }
    ps += __shfl_xor(ps, 1);
    ps += __shfl_xor(ps, 2);
    ps += __shfl_xor(ps, 4);
    ps += __shfl_xor(ps, 8);
    if (lr == 0) psum[q * 2 + half] = ps;
#pragma unroll
    for (int j = 0; j < 4; ++j) {
      int c = (2 * j + half) * 16 + lr;
      *(unsigned short*)(smem + XO + q * PS + c * 2) = f2bf(pv[r][j]);
    }
  }
  __syncthreads();  // B5: P, psum visible

  // ---- PV: wave (qt,half) computes h-tiles half*6..half*6+5 ----
  f32x4 o[6];
#pragma unroll
  for (int n = 0; n < 6; ++n) o[n] = zero;
  const int ktmax = qt / 2 + 1;  // causal: only k-tiles with t0 <= qt*16+15
  for (int kt = 0; kt < ktmax; ++kt) {
    int t0 = kt * 32 + lg * 8;
    short8 a = *(const short8*)(smem + XO + (qt * 16 + lr) * PS + t0 * 2);  // P
#pragma unroll
    for (int n = 0; n < 6; ++n) {
      int ht = half * 6 + n;
      short8 bb = *(const short8*)(smem + VO + (ht * 16 + lr) * VS + t0 * 2);  // V^T
      o[n] = __builtin_amdgcn_mfma_f32_16x16x32_bf16(a, bb, o[n], 0, 0, 0);
    }
  }

  // ---- epilogue: fold 1/rowsum, store fp32 ----
  float rinv[4];
#pragma unroll
  for (int r = 0; r < 4; ++r) {
    int q = qt * 16 + lg * 4 + r;
    rinv[r] = 1.0f / (psum[q * 2] + psum[q * 2 + 1]);
  }
  float* ob = out + (size_t)b * (TT * HH);
#pragma unroll
  for (int n = 0; n < 6; ++n)
#pragma unroll
    for (int r = 0; r < 4; ++r) {
      int q = qt * 16 + lg * 4 + r;
      ob[q * HH + (half * 6 + n) * 16 + lr] = o[n][r] * rinv[r];
    }
}

extern "C" void kernel_launch(void* const* d_in, const int* in_sizes, int n_in,
                              void* d_out, int out_size, void* d_ws, size_t ws_size,
                              hipStream_t stream) {
  const float* x  = (const float*)d_in[0];
  const float* Wq = (const float*)d_in[1];
  const float* Wk = (const float*)d_in[2];
  const float* Wv = (const float*)d_in[3];
  float* out = (float*)d_out;
  short* wsW = (short*)d_ws;
  int Bn = in_sizes[0] / (TT * EE);
  hipLaunchKernelGGL(cvt_w, dim3(108), dim3(256), 0, stream, Wq, Wk, Wv, wsW);
  hipLaunchKernelGGL(head_kernel, dim3(Bn), dim3(1024), LDS_TOTAL, stream,
                     x, wsW, out);
}